// Round 1
// baseline (75.751 us; speedup 1.0000x reference)
//
#include <hip/hip_runtime.h>

namespace {
constexpr int C = 128;
constexpr int P = 32;
constexpr int M = 2;
constexpr int HW = 256 * 256;
constexpr int B = 8;
constexpr int PPT = 4;                          // adjacent pixels per thread
constexpr int BLOCK = 256;
constexpr int PIX_PER_BLK = BLOCK * PPT;        // 1024
constexpr int BLKS_PER_IMG = HW / PIX_PER_BLK;  // 64

// ws layout (floats): [P] w2half | [P] alphap | [P] g2 | [P] U0 | [P] U1 | [C*P] Wt (Wt[c][p])
__global__ void prep_kernel(const float* __restrict__ Wp,
                            const float* __restrict__ beta,
                            const float* __restrict__ alpha,
                            const float* __restrict__ gam,
                            float* __restrict__ ws) {
  const int t = threadIdx.x;
  if (t < P) {
    const int p = t;
    float w2 = 0.f;
    for (int c = 0; c < C; ++c) {
      const float w = Wp[p * C + c];
      w2 = fmaf(w, w, w2);
    }
    ws[p] = 0.5f * w2;
    ws[P + p] = 0.99f / (1.f + __expf(-alpha[p]));
    const float g = gam[p];
    ws[2 * P + p] = g * g;
    const float b0 = beta[p * M + 0], b1 = beta[p * M + 1];
    const float q0 = b0 * b0, q1 = b1 * b1;
    const float inv = 1.f / (q0 + q1);
    ws[3 * P + p] = q0 * inv;
    ws[4 * P + p] = q1 * inv;
  }
  float* Wt = ws + 5 * P;
  for (int i = t; i < C * P; i += BLOCK) {
    const int c = i >> 5, p = i & 31;
    Wt[i] = Wp[p * C + c];
  }
}

__global__ __launch_bounds__(BLOCK) void evid_kernel(
    const float* __restrict__ x, const float* __restrict__ ws,
    float* __restrict__ out) {
  const float* __restrict__ Wt = ws + 5 * P;
  const int blk = blockIdx.x;
  const int b = blk / BLKS_PER_IMG;
  const int s0 = (blk % BLKS_PER_IMG) * PIX_PER_BLK + threadIdx.x * PPT;
  const float* __restrict__ xb = x + (size_t)b * C * HW + s0;

  float dot[P][PPT];
#pragma unroll
  for (int p = 0; p < P; ++p)
#pragma unroll
    for (int k = 0; k < PPT; ++k) dot[p][k] = 0.f;
  float x2[PPT] = {0.f, 0.f, 0.f, 0.f};

#pragma unroll 4
  for (int c = 0; c < C; ++c) {
    const float4 xv = *reinterpret_cast<const float4*>(xb + (size_t)c * HW);
    const float xa[PPT] = {xv.x, xv.y, xv.z, xv.w};
#pragma unroll
    for (int k = 0; k < PPT; ++k) x2[k] = fmaf(xa[k], xa[k], x2[k]);
#pragma unroll
    for (int p = 0; p < P; ++p) {
      const float wv = Wt[c * P + p];  // wave-uniform -> scalar load
#pragma unroll
      for (int k = 0; k < PPT; ++k) dot[p][k] = fmaf(xa[k], wv, dot[p][k]);
    }
  }

  float cls0[PPT], cls1[PPT], om[PPT];
#pragma unroll
  for (int k = 0; k < PPT; ++k) {
    cls0[k] = 0.f;
    cls1[k] = 0.f;
    om[k] = 1.f;
  }

#pragma unroll
  for (int p = 0; p < P; ++p) {
    const float w2h = ws[p];
    const float ap = ws[P + p];
    const float g2 = ws[2 * P + p];
    const float U0 = ws[3 * P + p];
    const float U1 = ws[4 * P + p];
#pragma unroll
    for (int k = 0; k < PPT; ++k) {
      const float d = fmaf(0.5f, x2[k], w2h) - dot[p][k];
      const float s = ap * __expf(-g2 * d);
      const float mO = 1.f - s;
      const float mj0 = U0 * s, mj1 = U1 * s;
      cls0[k] = cls0[k] * (mj0 + mO) + mj0 * om[k];
      cls1[k] = cls1[k] * (mj1 + mO) + mj1 * om[k];
      om[k] *= mO;
    }
  }

  float o0[PPT], o1[PPT], o2[PPT];
#pragma unroll
  for (int k = 0; k < PPT; ++k) {
    const float tot = cls0[k] + cls1[k] + om[k];
    const float inv = 1.f / tot;
    o0[k] = cls0[k] * inv;
    o1[k] = cls1[k] * inv;
    o2[k] = om[k] * inv;
  }
  float* ob = out + (size_t)b * 3 * HW + s0;
  *reinterpret_cast<float4*>(ob) = make_float4(o0[0], o0[1], o0[2], o0[3]);
  *reinterpret_cast<float4*>(ob + HW) = make_float4(o1[0], o1[1], o1[2], o1[3]);
  *reinterpret_cast<float4*>(ob + 2 * HW) = make_float4(o2[0], o2[1], o2[2], o2[3]);
}
}  // namespace

extern "C" void kernel_launch(void* const* d_in, const int* in_sizes, int n_in,
                              void* d_out, int out_size, void* d_ws, size_t ws_size,
                              hipStream_t stream) {
  const float* feats = (const float*)d_in[0];
  const float* Wp = (const float*)d_in[1];
  const float* beta = (const float*)d_in[2];
  const float* alpha = (const float*)d_in[3];
  const float* gam = (const float*)d_in[4];
  float* ws = (float*)d_ws;
  float* out = (float*)d_out;

  hipLaunchKernelGGL(prep_kernel, dim3(1), dim3(BLOCK), 0, stream, Wp, beta,
                     alpha, gam, ws);
  hipLaunchKernelGGL(evid_kernel, dim3(B * BLKS_PER_IMG), dim3(BLOCK), 0,
                     stream, feats, ws, out);
}